// Round 9
// baseline (829.836 us; speedup 1.0000x reference)
//
#include <hip/hip_runtime.h>
#include <hip/hip_bf16.h>
#include <hip/hip_cooperative_groups.h>

namespace cg = cooperative_groups;

// Problem constants (fixed by setup_inputs)
constexpr int B_ = 64, L_ = 512, H_ = 768, T_ = 256, S_ = 128, D_ = 8;
constexpr int N_ = B_ * S_;        // 8192 nodes
constexpr int E0_ = 16 * N_;       // 131072 random edges
constexpr int NE_ = E0_ + N_;      // + self loops = 139264
constexpr float NEG_SLOPE = 0.2f;
constexpr int KDIM = 768;          // GEMM K (= H_)
constexpr int NB_WT = 3 * 576;     // W-transpose blocks
constexpr int NB_ZERO = 68;        // zero-fill blocks (68*256 int4 = 272 KB)
constexpr int MEGA_GRID = 512;     // 2 blocks/CU -> coop launch always valid

typedef __attribute__((ext_vector_type(8))) short short8v;
typedef __attribute__((ext_vector_type(4))) float f32x4;

#define GLOAD_LDS16(g, l) __builtin_amdgcn_global_load_lds( \
    (const __attribute__((address_space(1))) void*)(g), \
    (__attribute__((address_space(3))) void*)(l), 16, 0, 0)

__device__ __forceinline__ float bf2f(short s) {
  unsigned u = ((unsigned)(unsigned short)s) << 16;
  return __builtin_bit_cast(float, u);
}
__device__ __forceinline__ short f2bf(float f) {
  return (short)__bfloat16_as_ushort(__float2bfloat16(f));
}
__device__ __forceinline__ int docof(int b, const int* __restrict__ doc_spans) {
  int cnt = 0;
  for (int dd = 0; dd < D_; dd++) cnt += (doc_spans[dd * 2] <= b) ? 1 : 0;
  return cnt - 1;
}

// -- fused: token pooling [0,N) + W transpose [N,N+1728) + zero-fill (rest) --
__global__ __launch_bounds__(256) void k_token_wt(const float* __restrict__ features,
                                                  const int* __restrict__ token_spans,
                                                  const int* __restrict__ masks,
                                                  const int* __restrict__ selidx,
                                                  __hip_bfloat16* __restrict__ h0,
                                                  const float* __restrict__ W0,
                                                  const float* __restrict__ W1,
                                                  const float* __restrict__ W2,
                                                  __hip_bfloat16* __restrict__ Wt,
                                                  int4* __restrict__ zero_base) {
  int bid = blockIdx.x;
  if (bid < N_) {
    if (threadIdx.x >= 192) return;
    int n = bid;
    int b = n / S_;
    int t = selidx[n];
    int st = token_spans[(b * T_ + t) * 2 + 0];
    int en = token_spans[(b * T_ + t) * 2 + 1];
    int tid = threadIdx.x;
    float4 a = make_float4(0.f, 0.f, 0.f, 0.f);
    int cnt = 0;
    for (int l = st; l < en; l++) {
      if (masks[b * L_ + l] > 0) {
        cnt++;
        float4 v = ((const float4*)(features + ((size_t)b * L_ + l) * H_))[tid];
        a.x += v.x; a.y += v.y; a.z += v.z; a.w += v.w;
      }
    }
    float sc = (en > 0) ? (1.0f / (float)max(cnt, 1)) : 0.0f;
    short4 o;
    o.x = f2bf(a.x * sc); o.y = f2bf(a.y * sc); o.z = f2bf(a.z * sc); o.w = f2bf(a.w * sc);
    ((short4*)(h0 + (size_t)n * H_))[tid] = o;
    return;
  }
  if (bid < N_ + NB_WT) {
    int wb = bid - N_;                     // 0..1727
    int layer = wb / 576;
    int rem = wb % 576;
    int k0 = (rem % 24) * 32, n0 = (rem / 24) * 32;
    const float* Ws[3] = {W0, W1, W2};
    const float* W = Ws[layer];
    __hip_bfloat16* O = Wt + (size_t)layer * H_ * H_;
    __shared__ float tbuf[32][33];
    int x = threadIdx.x % 32, y = threadIdx.x / 32;   // 32x8
    for (int i = 0; i < 32; i += 8)
      tbuf[y + i][x] = W[(size_t)(k0 + y + i) * H_ + n0 + x];
    __syncthreads();
    for (int i = 0; i < 32; i += 8)
      O[(size_t)(n0 + y + i) * H_ + k0 + x] = __float2bfloat16(tbuf[x][y + i]);
    return;
  }
  int zi = bid - N_ - NB_WT;
  zero_base[zi * 256 + threadIdx.x] = make_int4(0, 0, 0, 0);
}

// ========================= device helpers (shared) =========================
__device__ __forceinline__ void gemm_tile_body(
    int bm, int bn, int tid, int wv, int lane,
    const __hip_bfloat16* __restrict__ hA, const __hip_bfloat16* __restrict__ Bt,
    unsigned char* __restrict__ hB,
    const float* __restrict__ al, const float* __restrict__ ar,
    float* __restrict__ elp, float* __restrict__ erp,
    short (*smA)[128 * 32], short (*smB)[128 * 32]) {
  int wr = wv >> 1, wc = wv & 1;
  int lr = lane & 15;
  int lk = (lane >> 4) * 8;
  f32x4 acc[4][4] = {};

  const __hip_bfloat16* gA[2];
  const __hip_bfloat16* gB[2];
  int ldsoff[2];
#pragma unroll
  for (int i = 0; i < 2; i++) {
    int idx = i * 256 + tid;
    int row = idx >> 2;
    int ck = (idx & 3) * 8;
    gA[i] = hA + (size_t)(bm + row) * KDIM + ck;
    gB[i] = Bt + (size_t)(bn + row) * KDIM + ck;
    ldsoff[i] = idx * 8;
  }
#pragma unroll
  for (int i = 0; i < 2; i++) GLOAD_LDS16(gA[i], &smA[0][ldsoff[i]]);
#pragma unroll
  for (int i = 0; i < 2; i++) GLOAD_LDS16(gB[i], &smB[0][ldsoff[i]]);
  __syncthreads();

  constexpr int NT = KDIM / 32;
  for (int t = 0; t < NT; t++) {
    int cur = t & 1;
    if (t < NT - 1) {
      int k0 = (t + 1) * 32;
#pragma unroll
      for (int i = 0; i < 2; i++) GLOAD_LDS16(gA[i] + k0, &smA[cur ^ 1][ldsoff[i]]);
#pragma unroll
      for (int i = 0; i < 2; i++) GLOAD_LDS16(gB[i] + k0, &smB[cur ^ 1][ldsoff[i]]);
    }
    short8v a_frag[4], b_frag[4];
#pragma unroll
    for (int m = 0; m < 4; m++)
      a_frag[m] = *(const short8v*)&smA[cur][(wr * 64 + m * 16 + lr) * 32 + lk];
#pragma unroll
    for (int n = 0; n < 4; n++)
      b_frag[n] = *(const short8v*)&smB[cur][(wc * 64 + n * 16 + lr) * 32 + lk];
#pragma unroll
    for (int m = 0; m < 4; m++)
#pragma unroll
      for (int n = 0; n < 4; n++)
        acc[m][n] = __builtin_amdgcn_mfma_f32_16x16x32_bf16(a_frag[m], b_frag[n], acc[m][n], 0, 0, 0);
    __syncthreads();
  }

  float alv[4], arv[4];
#pragma unroll
  for (int n = 0; n < 4; n++) {
    int col = bn + wc * 64 + n * 16 + lr;
    alv[n] = al[col]; arv[n] = ar[col];
  }
  // C/D layout: col = lane&15, row = (lane>>4)*4 + r  [verified m89/m91]
#pragma unroll
  for (int m = 0; m < 4; m++) {
    int rbase = bm + wr * 64 + m * 16 + (lane >> 4) * 4;
#pragma unroll
    for (int n = 0; n < 4; n++) {
      int col = bn + wc * 64 + n * 16 + lr;
#pragma unroll
      for (int r = 0; r < 4; r++) {
        float v = acc[m][n][r];
        int pk = __builtin_amdgcn_cvt_pk_fp8_f32(v, v, 0, false);
        hB[(size_t)(rbase + r) * H_ + col] = (unsigned char)(pk & 0xff);
      }
    }
#pragma unroll
    for (int r = 0; r < 4; r++) {
      float pel = 0.f, per_ = 0.f;
#pragma unroll
      for (int n = 0; n < 4; n++) {
        pel  += acc[m][n][r] * alv[n];
        per_ += acc[m][n][r] * arv[n];
      }
#pragma unroll
      for (int off2 = 1; off2 < 16; off2 <<= 1) {
        pel  += __shfl_xor(pel,  off2);
        per_ += __shfl_xor(per_, off2);
      }
      if (lr == 0) {
        atomicAdd(&elp[rbase + r], pel);
        atomicAdd(&erp[rbase + r], per_);
      }
    }
  }
}

__device__ __forceinline__ void agg_node_body(
    int n, int lane,
    const unsigned char* __restrict__ hB,
    const float* __restrict__ elp, const float* __restrict__ erp,
    const int* __restrict__ offs, const int* __restrict__ esrc,
    __hip_bfloat16* __restrict__ hA) {
  int o0 = offs[n];
  int deg = offs[n + 1] - o0;
  float ern = erp[n];
  float acc[12] = {};

  if (deg <= 64) {
    float w_ = 0.f; int s_ = 0;
    if (lane < deg) {
      s_ = esrc[o0 + lane];
      float v = elp[s_] + ern;
      w_ = v > 0.f ? v : NEG_SLOPE * v;
    } else {
      w_ = -1e30f;
    }
    float m = w_;
    for (int off2 = 32; off2; off2 >>= 1) m = fmaxf(m, __shfl_xor(m, off2));
    float ex = (lane < deg) ? __expf(w_ - m) : 0.f;
    float sum = ex;
    for (int off2 = 32; off2; off2 >>= 1) sum += __shfl_xor(sum, off2);
    w_ = ex / sum;
    for (int j = 0; j < deg; j++) {
      float wj = __shfl(w_, j);
      int sj = __shfl(s_, j);
      const unsigned* zr = (const unsigned*)(hB + (size_t)sj * H_);
#pragma unroll
      for (int i = 0; i < 3; i++) {
        unsigned u = zr[lane + i * 64];
        acc[i * 4 + 0] += wj * __builtin_amdgcn_cvt_f32_fp8(u, 0);
        acc[i * 4 + 1] += wj * __builtin_amdgcn_cvt_f32_fp8(u, 1);
        acc[i * 4 + 2] += wj * __builtin_amdgcn_cvt_f32_fp8(u, 2);
        acc[i * 4 + 3] += wj * __builtin_amdgcn_cvt_f32_fp8(u, 3);
      }
    }
  } else {
    float lmax = -1e30f;
    for (int i = lane; i < deg; i += 64) {
      float v = elp[esrc[o0 + i]] + ern;
      v = v > 0.f ? v : NEG_SLOPE * v;
      lmax = fmaxf(lmax, v);
    }
    for (int off2 = 32; off2; off2 >>= 1) lmax = fmaxf(lmax, __shfl_xor(lmax, off2));
    float lsum = 0.f;
    for (int i = lane; i < deg; i += 64) {
      float v = elp[esrc[o0 + i]] + ern;
      v = v > 0.f ? v : NEG_SLOPE * v;
      lsum += __expf(v - lmax);
    }
    for (int off2 = 32; off2; off2 >>= 1) lsum += __shfl_xor(lsum, off2);
    float inv = 1.0f / lsum;
    for (int base = 0; base < deg; base += 64) {
      int chunk = min(64, deg - base);
      float w_ = 0.f; int s_ = 0;
      if (lane < chunk) {
        s_ = esrc[o0 + base + lane];
        float v = elp[s_] + ern;
        v = v > 0.f ? v : NEG_SLOPE * v;
        w_ = __expf(v - lmax) * inv;
      }
      for (int j = 0; j < chunk; j++) {
        float wj = __shfl(w_, j);
        int sj = __shfl(s_, j);
        const unsigned* zr = (const unsigned*)(hB + (size_t)sj * H_);
#pragma unroll
        for (int i = 0; i < 3; i++) {
          unsigned u = zr[lane + i * 64];
          acc[i * 4 + 0] += wj * __builtin_amdgcn_cvt_f32_fp8(u, 0);
          acc[i * 4 + 1] += wj * __builtin_amdgcn_cvt_f32_fp8(u, 1);
          acc[i * 4 + 2] += wj * __builtin_amdgcn_cvt_f32_fp8(u, 2);
          acc[i * 4 + 3] += wj * __builtin_amdgcn_cvt_f32_fp8(u, 3);
        }
      }
    }
  }

  short4* ho = (short4*)(hA + (size_t)n * H_);
#pragma unroll
  for (int i = 0; i < 3; i++) {
    float e0 = acc[i * 4 + 0]; e0 = e0 > 0.f ? e0 : __expf(e0) - 1.f;
    float e1 = acc[i * 4 + 1]; e1 = e1 > 0.f ? e1 : __expf(e1) - 1.f;
    float e2 = acc[i * 4 + 2]; e2 = e2 > 0.f ? e2 : __expf(e2) - 1.f;
    float e3 = acc[i * 4 + 3]; e3 = e3 > 0.f ? e3 : __expf(e3) - 1.f;
    short4 o; o.x = f2bf(e0); o.y = f2bf(e1); o.z = f2bf(e2); o.w = f2bf(e3);
    ho[lane + i * 64] = o;
  }
}

// ===================== cooperative mega-kernel =============================
__global__ __launch_bounds__(256, 2) void k_mega(
    const int* __restrict__ dstv, const int* __restrict__ srcv,
    int* __restrict__ counts, int* __restrict__ offs, int* __restrict__ cursor,
    int* __restrict__ esrc,
    __hip_bfloat16* __restrict__ hA, unsigned char* __restrict__ hB,
    const __hip_bfloat16* __restrict__ Wt,
    const float* __restrict__ al0, const float* __restrict__ ar0,
    const float* __restrict__ al1, const float* __restrict__ ar1,
    const float* __restrict__ al2, const float* __restrict__ ar2,
    float* __restrict__ el, float* __restrict__ er,
    const float* __restrict__ features, const int* __restrict__ masks,
    const int* __restrict__ segment_ids, const int* __restrict__ is_head,
    const int* __restrict__ doc_spans,
    float* __restrict__ avgp, float* __restrict__ qfp, float* __restrict__ out) {
  cg::grid_group grid = cg::this_grid();
  int tid = threadIdx.x;
  int wv = tid >> 6, lane = tid & 63;

  __shared__ union SM {
    struct { short A[2][128 * 32]; short B[2][128 * 32]; } g;  // 32 KB gemm staging
    int part[256];                                             // scan partials
    float qm[64];                                              // qf row mask
  } sm;

  // ---- P0: CSR degree count ----
  for (int i = blockIdx.x * 256 + tid; i < NE_; i += MEGA_GRID * 256)
    atomicAdd(&counts[dstv[i]], 1);
  grid.sync();

  // ---- P1: exclusive scan (block 0) ----
  if (blockIdx.x == 0) {
    int base = tid * 32;
    int s = 0;
    for (int i = 0; i < 32; i++) s += counts[base + i];
    sm.part[tid] = s;
    __syncthreads();
    for (int off2 = 1; off2 < 256; off2 <<= 1) {
      int v = (tid >= off2) ? sm.part[tid - off2] : 0;
      __syncthreads();
      sm.part[tid] += v;
      __syncthreads();
    }
    int run = tid ? sm.part[tid - 1] : 0;
    for (int i = 0; i < 32; i++) {
      offs[base + i] = run;
      cursor[base + i] = run;
      run += counts[base + i];
    }
    if (tid == 255) offs[N_] = run;
  }
  grid.sync();

  // ---- P2: scatter source ids sorted by dst ----
  for (int i = blockIdx.x * 256 + tid; i < NE_; i += MEGA_GRID * 256) {
    int p = atomicAdd(&cursor[dstv[i]], 1);
    esrc[p] = srcv[i];
  }
  grid.sync();

  // ---- P3/P4 x3: GEMM (+el/er) then agg ----
#pragma unroll 1
  for (int layer = 0; layer < 3; layer++) {
    const float* al = layer == 0 ? al0 : (layer == 1 ? al1 : al2);
    const float* ar = layer == 0 ? ar0 : (layer == 1 ? ar1 : ar2);
    float* elp = el + layer * N_;
    float* erp = er + layer * N_;
    const __hip_bfloat16* Bt = Wt + (size_t)layer * H_ * H_;

    constexpr int NTILE = (N_ / 128) * (H_ / 128);   // 384
    for (int tile = blockIdx.x; tile < NTILE; tile += MEGA_GRID) {
      int bm = (tile % (N_ / 128)) * 128;
      int bn = (tile / (N_ / 128)) * 128;
      gemm_tile_body(bm, bn, tid, wv, lane, hA, Bt, hB, al, ar, elp, erp, sm.g.A, sm.g.B);
    }
    grid.sync();

    for (int g = blockIdx.x; g < N_ / 4; g += MEGA_GRID)
      agg_node_body(g * 4 + wv, lane, hB, elp, erp, offs, esrc, hA);
    grid.sync();
  }

  // ---- P5: avg (units 0..511) + qf (units 512..1023) ----
  for (int u = blockIdx.x; u < 1024; u += MEGA_GRID) {
    if (u < 512) {
      int b = u >> 3, s0 = (u & 7) * 16;
      if (tid < 192) {
        float4 a = make_float4(0.f, 0.f, 0.f, 0.f);
        for (int i = 0; i < 16; i++) {
          short4 v = ((const short4*)(hA + ((size_t)(b * S_ + s0 + i)) * H_))[tid];
          a.x += bf2f(v.x); a.y += bf2f(v.y); a.z += bf2f(v.z); a.w += bf2f(v.w);
        }
        int d = docof(b, doc_spans);
        atomicAdd(&avgp[d * H_ + tid * 4 + 0], a.x);
        atomicAdd(&avgp[d * H_ + tid * 4 + 1], a.y);
        atomicAdd(&avgp[d * H_ + tid * 4 + 2], a.z);
        atomicAdd(&avgp[d * H_ + tid * 4 + 3], a.w);
      }
    } else {
      int vq = u - 512;
      int b = vq >> 3, l0 = (vq & 7) * 64;
      __syncthreads();
      if (tid < 64) {
        int l = l0 + tid;
        sm.qm[tid] = (is_head[b * L_ + l] != 2 && segment_ids[b * L_ + l] == 0 && masks[b * L_ + l] > 0) ? 1.0f : 0.0f;
      }
      __syncthreads();
      if (tid < 192) {
        float4 a = make_float4(0.f, 0.f, 0.f, 0.f);
        for (int i = 0; i < 64; i++) {
          if (sm.qm[i] != 0.f) {
            float4 v = ((const float4*)(features + ((size_t)b * L_ + l0 + i) * H_))[tid];
            a.x += v.x; a.y += v.y; a.z += v.z; a.w += v.w;
          }
        }
        int d = docof(b, doc_spans);
        atomicAdd(&qfp[d * H_ + tid * 4 + 0], a.x);
        atomicAdd(&qfp[d * H_ + tid * 4 + 1], a.y);
        atomicAdd(&qfp[d * H_ + tid * 4 + 2], a.z);
        atomicAdd(&qfp[d * H_ + tid * 4 + 3], a.w);
      }
    }
  }
  grid.sync();

  // ---- P6: final (block 0) ----
  if (blockIdx.x == 0) {
    int ds[16];
#pragma unroll
    for (int i = 0; i < 16; i++) ds[i] = doc_spans[i];
    for (int d = wv; d < D_; d += 4) {
      int nsent = 0;
      for (int b = 0; b < B_; b++) {
        int cnt = 0;
#pragma unroll
        for (int dd = 0; dd < D_; dd++) cnt += (ds[dd * 2] <= b) ? 1 : 0;
        nsent += ((cnt - 1) == d) ? 1 : 0;
      }
      float inv_node = 1.0f / fmaxf((float)nsent * (float)S_, 1.0f);
      float inv_doc  = 1.0f / fmaxf((float)(ds[d * 2 + 1] - ds[d * 2]), 1.0f);
      float acc = 0.f;
      for (int h = lane; h < H_; h += 64)
        acc += fabsf(qfp[d * H_ + h] * inv_doc - avgp[d * H_ + h] * inv_node);
      for (int off2 = 32; off2; off2 >>= 1) acc += __shfl_xor(acc, off2);
      if (lane == 0) out[d] = acc;
    }
  }
}

// ===================== fallback dispatch-chain kernels =====================
__global__ void k_count(const int* __restrict__ dst, int* __restrict__ counts, int ne) {
  int i = blockIdx.x * 256 + threadIdx.x;
  if (i < ne) atomicAdd(&counts[dst[i]], 1);
}

__global__ __launch_bounds__(1024) void k_scan(const int* __restrict__ counts,
                                               int* __restrict__ offs,
                                               int* __restrict__ cursor) {
  __shared__ int part[1024];
  int tid = threadIdx.x;
  int base = tid * 8;
  int loc[8];
  int s = 0;
  for (int i = 0; i < 8; i++) { loc[i] = s; s += counts[base + i]; }
  part[tid] = s;
  __syncthreads();
  for (int off = 1; off < 1024; off <<= 1) {
    int v = (tid >= off) ? part[tid - off] : 0;
    __syncthreads();
    part[tid] += v;
    __syncthreads();
  }
  int excl = (tid == 0) ? 0 : part[tid - 1];
  for (int i = 0; i < 8; i++) {
    int o = excl + loc[i];
    offs[base + i] = o;
    cursor[base + i] = o;
  }
  if (tid == 1023) offs[N_] = part[1023];
}

__global__ void k_scatter(const int* __restrict__ dst, const int* __restrict__ src,
                          int* __restrict__ cursor, int* __restrict__ esrc, int ne) {
  int i = blockIdx.x * 256 + threadIdx.x;
  if (i < ne) { int p = atomicAdd(&cursor[dst[i]], 1); esrc[p] = src[i]; }
}

__global__ __launch_bounds__(256) void k_gemm_bf16(const __hip_bfloat16* __restrict__ A,
                                                   const __hip_bfloat16* __restrict__ Bt,
                                                   unsigned char* __restrict__ C,
                                                   const float* __restrict__ al,
                                                   const float* __restrict__ ar,
                                                   float* __restrict__ el,
                                                   float* __restrict__ er) {
  __shared__ short As[2][128 * 32];
  __shared__ short Bs[2][128 * 32];
  int tid = threadIdx.x;
  gemm_tile_body(blockIdx.x * 128, blockIdx.y * 128, tid, tid >> 6, tid & 63,
                 A, Bt, C, al, ar, el, er, As, Bs);
}

__global__ __launch_bounds__(256) void k_agg(const unsigned char* __restrict__ z,
                                             const float* __restrict__ el,
                                             const float* __restrict__ er,
                                             const int* __restrict__ offs,
                                             const int* __restrict__ esrc,
                                             __hip_bfloat16* __restrict__ hout) {
  int wv = threadIdx.x >> 6, lane = threadIdx.x & 63;
  agg_node_body(blockIdx.x * 4 + wv, lane, z, el, er, offs, esrc, hout);
}

__global__ __launch_bounds__(192) void k_avgqf(const __hip_bfloat16* __restrict__ h,
                                               const float* __restrict__ features,
                                               const int* __restrict__ masks,
                                               const int* __restrict__ segment_ids,
                                               const int* __restrict__ is_head,
                                               const int* __restrict__ doc_spans,
                                               float* __restrict__ avgp,
                                               float* __restrict__ qfp) {
  int b = blockIdx.x;
  int y = blockIdx.y;
  int tid = threadIdx.x;
  int d = docof(b, doc_spans);
  if (y < 8) {
    int s0 = y * 16;
    float4 a = make_float4(0.f, 0.f, 0.f, 0.f);
    for (int i = 0; i < 16; i++) {
      short4 v = ((const short4*)(h + ((size_t)(b * S_ + s0 + i)) * H_))[tid];
      a.x += bf2f(v.x); a.y += bf2f(v.y); a.z += bf2f(v.z); a.w += bf2f(v.w);
    }
    atomicAdd(&avgp[d * H_ + tid * 4 + 0], a.x);
    atomicAdd(&avgp[d * H_ + tid * 4 + 1], a.y);
    atomicAdd(&avgp[d * H_ + tid * 4 + 2], a.z);
    atomicAdd(&avgp[d * H_ + tid * 4 + 3], a.w);
  } else {
    int l0 = (y - 8) * 64;
    __shared__ float qm[64];
    if (tid < 64) {
      int l = l0 + tid;
      qm[tid] = (is_head[b * L_ + l] != 2 && segment_ids[b * L_ + l] == 0 && masks[b * L_ + l] > 0) ? 1.0f : 0.0f;
    }
    __syncthreads();
    float4 a = make_float4(0.f, 0.f, 0.f, 0.f);
    for (int i = 0; i < 64; i++) {
      if (qm[i] != 0.f) {
        float4 v = ((const float4*)(features + ((size_t)b * L_ + l0 + i) * H_))[tid];
        a.x += v.x; a.y += v.y; a.z += v.z; a.w += v.w;
      }
    }
    atomicAdd(&qfp[d * H_ + tid * 4 + 0], a.x);
    atomicAdd(&qfp[d * H_ + tid * 4 + 1], a.y);
    atomicAdd(&qfp[d * H_ + tid * 4 + 2], a.z);
    atomicAdd(&qfp[d * H_ + tid * 4 + 3], a.w);
  }
}

__global__ __launch_bounds__(512) void k_final(const float* __restrict__ qfp,
                                               const float* __restrict__ avgp,
                                               const int* __restrict__ doc_spans,
                                               float* __restrict__ out) {
  __shared__ int ds[D_ * 2];
  int tid = threadIdx.x;
  if (tid < D_ * 2) ds[tid] = doc_spans[tid];
  __syncthreads();
  int d = tid >> 6, lane = tid & 63;
  int nsent = 0;
  for (int b = 0; b < B_; b++) {
    int cnt = 0;
#pragma unroll
    for (int dd = 0; dd < D_; dd++) cnt += (ds[dd * 2] <= b) ? 1 : 0;
    nsent += ((cnt - 1) == d) ? 1 : 0;
  }
  float inv_node = 1.0f / fmaxf((float)nsent * (float)S_, 1.0f);
  float inv_doc  = 1.0f / fmaxf((float)(ds[d * 2 + 1] - ds[d * 2]), 1.0f);
  float acc = 0.f;
  for (int h = lane; h < H_; h += 64)
    acc += fabsf(qfp[d * H_ + h] * inv_doc - avgp[d * H_ + h] * inv_node);
  for (int off = 32; off; off >>= 1) acc += __shfl_xor(acc, off);
  if (lane == 0) out[d] = acc;
}

extern "C" void kernel_launch(void* const* d_in, const int* in_sizes, int n_in,
                              void* d_out, int out_size, void* d_ws, size_t ws_size,
                              hipStream_t stream) {
  const float* features     = (const float*)d_in[0];
  const int*   token_spans  = (const int*)d_in[1];
  const int*   masks        = (const int*)d_in[2];
  const int*   selidx       = (const int*)d_in[3];
  const int*   src          = (const int*)d_in[4];
  const int*   dst          = (const int*)d_in[5];
  const int*   doc_spans    = (const int*)d_in[6];
  const int*   segment_ids  = (const int*)d_in[7];
  const int*   is_head      = (const int*)d_in[8];
  const float* W0  = (const float*)d_in[9];
  const float* al0 = (const float*)d_in[10];
  const float* ar0 = (const float*)d_in[11];
  const float* W1  = (const float*)d_in[12];
  const float* al1 = (const float*)d_in[13];
  const float* ar1 = (const float*)d_in[14];
  const float* W2  = (const float*)d_in[15];
  const float* al2 = (const float*)d_in[16];
  const float* ar2 = (const float*)d_in[17];
  float* out = (float*)d_out;

  char* ws = (char*)d_ws;
  size_t off = 0;
  auto alloc = [&](size_t bytes) -> void* {
    void* p = ws + off;
    off = (off + bytes + 255) & ~(size_t)255;
    return p;
  };
  __hip_bfloat16* hA = (__hip_bfloat16*)alloc((size_t)N_ * H_ * 2);   // bf16 h
  unsigned char*  hB = (unsigned char*)alloc((size_t)N_ * H_);        // fp8 z
  __hip_bfloat16* Wt = (__hip_bfloat16*)alloc((size_t)3 * H_ * H_ * 2);
  // ---- contiguous zero-fill region: avgp|qfp | el[3] | er[3] | counts ----
  float* avgp   = (float*)alloc((size_t)2 * D_ * H_ * 4);  // avgp | qfp
  float* qfp    = avgp + (size_t)D_ * H_;
  float* el     = (float*)alloc((size_t)3 * N_ * 4);
  float* er     = (float*)alloc((size_t)3 * N_ * 4);
  int*   counts = (int*)alloc((size_t)N_ * 4);
  // total = (2*8*768 + 6*8192 + 8192)*4 = 278528 B = 68 blocks * 256 * 16 B
  int*   offs   = (int*)alloc((size_t)(N_ + 1) * 4);
  int*   cursor = (int*)alloc((size_t)N_ * 4);
  int*   esrc   = (int*)alloc((size_t)NE_ * 4);

  // dispatch 1: token pooling + W transposes + zero-fill
  k_token_wt<<<N_ + NB_WT + NB_ZERO, 256, 0, stream>>>(features, token_spans, masks, selidx,
                                                       hA, W0, W1, W2, Wt,
                                                       (int4*)avgp);

  // dispatch 2: grid-synced cooperative kernel (512 blocks -> 2/CU, always fits)
  void* args[] = {
    (void*)&dst, (void*)&src, (void*)&counts, (void*)&offs, (void*)&cursor, (void*)&esrc,
    (void*)&hA, (void*)&hB, (void*)&Wt,
    (void*)&al0, (void*)&ar0, (void*)&al1, (void*)&ar1, (void*)&al2, (void*)&ar2,
    (void*)&el, (void*)&er,
    (void*)&features, (void*)&masks, (void*)&segment_ids, (void*)&is_head, (void*)&doc_spans,
    (void*)&avgp, (void*)&qfp, (void*)&out
  };
  hipError_t cerr = hipLaunchCooperativeKernel((void*)k_mega, dim3(MEGA_GRID), dim3(256),
                                               args, 0, stream);
  if (cerr != hipSuccess) {
    // fallback: proven multi-dispatch chain (identical math)
    k_count<<<(NE_ + 255) / 256, 256, 0, stream>>>(dst, counts, NE_);
    k_scan<<<1, 1024, 0, stream>>>(counts, offs, cursor);
    k_scatter<<<(NE_ + 255) / 256, 256, 0, stream>>>(dst, src, cursor, esrc, NE_);
    const float* alv[3] = {al0, al1, al2};
    const float* arv[3] = {ar0, ar1, ar2};
    for (int i = 0; i < 3; i++) {
      k_gemm_bf16<<<dim3(N_ / 128, H_ / 128), 256, 0, stream>>>(
          hA, Wt + (size_t)i * H_ * H_, hB, alv[i], arv[i],
          el + (size_t)i * N_, er + (size_t)i * N_);
      k_agg<<<N_ / 4, 256, 0, stream>>>(hB, el + (size_t)i * N_, er + (size_t)i * N_,
                                        offs, esrc, hA);
    }
    k_avgqf<<<dim3(B_, 16), 192, 0, stream>>>(hA, features, masks, segment_ids, is_head,
                                              doc_spans, avgp, qfp);
    k_final<<<1, 512, 0, stream>>>(qfp, avgp, doc_spans, out);
  }
}

// Round 10
// 210.302 us; speedup vs baseline: 3.9459x; 3.9459x over previous
//
#include <hip/hip_runtime.h>
#include <hip/hip_bf16.h>

// Problem constants (fixed by setup_inputs)
constexpr int B_ = 64, L_ = 512, H_ = 768, T_ = 256, S_ = 128, D_ = 8;
constexpr int N_ = B_ * S_;        // 8192 nodes
constexpr int E0_ = 16 * N_;       // 131072 random edges
constexpr int NE_ = E0_ + N_;      // + self loops = 139264
constexpr float NEG_SLOPE = 0.2f;
constexpr int KDIM = 768;          // GEMM K (= H_)
constexpr int NB_WT = 3 * 576;     // W-transpose blocks
constexpr int NB_ZERO = 68;        // zero-fill blocks (68*256 int4 = 272 KB)

typedef __attribute__((ext_vector_type(8))) short short8v;
typedef __attribute__((ext_vector_type(4))) float f32x4;

#define GLOAD_LDS16(g, l) __builtin_amdgcn_global_load_lds( \
    (const __attribute__((address_space(1))) void*)(g), \
    (__attribute__((address_space(3))) void*)(l), 16, 0, 0)

__device__ __forceinline__ float bf2f(short s) {
  unsigned u = ((unsigned)(unsigned short)s) << 16;
  return __builtin_bit_cast(float, u);
}
__device__ __forceinline__ short f2bf(float f) {
  return (short)__bfloat16_as_ushort(__float2bfloat16(f));
}
__device__ __forceinline__ int docof(int b, const int* __restrict__ doc_spans) {
  int cnt = 0;
  for (int dd = 0; dd < D_; dd++) cnt += (doc_spans[dd * 2] <= b) ? 1 : 0;
  return cnt - 1;
}

// -- fused: token pooling [0,N) + W transpose [N,N+1728) + zero-fill (rest) --
__global__ __launch_bounds__(256) void k_token_wt(const float* __restrict__ features,
                                                  const int* __restrict__ token_spans,
                                                  const int* __restrict__ masks,
                                                  const int* __restrict__ selidx,
                                                  __hip_bfloat16* __restrict__ h0,
                                                  const float* __restrict__ W0,
                                                  const float* __restrict__ W1,
                                                  const float* __restrict__ W2,
                                                  __hip_bfloat16* __restrict__ Wt,
                                                  int4* __restrict__ zero_base) {
  int bid = blockIdx.x;
  if (bid < N_) {
    if (threadIdx.x >= 192) return;
    int n = bid;
    int b = n / S_;
    int t = selidx[n];
    int st = token_spans[(b * T_ + t) * 2 + 0];
    int en = token_spans[(b * T_ + t) * 2 + 1];
    int tid = threadIdx.x;
    float4 a = make_float4(0.f, 0.f, 0.f, 0.f);
    int cnt = 0;
    for (int l = st; l < en; l++) {
      if (masks[b * L_ + l] > 0) {
        cnt++;
        float4 v = ((const float4*)(features + ((size_t)b * L_ + l) * H_))[tid];
        a.x += v.x; a.y += v.y; a.z += v.z; a.w += v.w;
      }
    }
    float sc = (en > 0) ? (1.0f / (float)max(cnt, 1)) : 0.0f;
    short4 o;
    o.x = f2bf(a.x * sc); o.y = f2bf(a.y * sc); o.z = f2bf(a.z * sc); o.w = f2bf(a.w * sc);
    ((short4*)(h0 + (size_t)n * H_))[tid] = o;
    return;
  }
  if (bid < N_ + NB_WT) {
    int wb = bid - N_;                     // 0..1727
    int layer = wb / 576;
    int rem = wb % 576;
    int k0 = (rem % 24) * 32, n0 = (rem / 24) * 32;
    const float* Ws[3] = {W0, W1, W2};
    const float* W = Ws[layer];
    __hip_bfloat16* O = Wt + (size_t)layer * H_ * H_;
    __shared__ float tbuf[32][33];
    int x = threadIdx.x % 32, y = threadIdx.x / 32;   // 32x8
    for (int i = 0; i < 32; i += 8)
      tbuf[y + i][x] = W[(size_t)(k0 + y + i) * H_ + n0 + x];
    __syncthreads();
    for (int i = 0; i < 32; i += 8)
      O[(size_t)(n0 + y + i) * H_ + k0 + x] = __float2bfloat16(tbuf[x][y + i]);
    return;
  }
  int zi = bid - N_ - NB_WT;
  zero_base[zi * 256 + threadIdx.x] = make_int4(0, 0, 0, 0);
}

// ---------------- CSR build (edges constant across layers) ----------------
__global__ void k_count(const int* __restrict__ dst, int* __restrict__ counts, int ne) {
  int i = blockIdx.x * 256 + threadIdx.x;
  if (i < ne) atomicAdd(&counts[dst[i]], 1);
}

__global__ __launch_bounds__(1024) void k_scan(const int* __restrict__ counts,
                                               int* __restrict__ offs,
                                               int* __restrict__ cursor) {
  __shared__ int part[1024];
  int tid = threadIdx.x;
  int base = tid * 8;
  int loc[8];
  int s = 0;
  for (int i = 0; i < 8; i++) { loc[i] = s; s += counts[base + i]; }
  part[tid] = s;
  __syncthreads();
  for (int off = 1; off < 1024; off <<= 1) {
    int v = (tid >= off) ? part[tid - off] : 0;
    __syncthreads();
    part[tid] += v;
    __syncthreads();
  }
  int excl = (tid == 0) ? 0 : part[tid - 1];
  for (int i = 0; i < 8; i++) {
    int o = excl + loc[i];
    offs[base + i] = o;
    cursor[base + i] = o;
  }
  if (tid == 1023) offs[N_] = part[1023];
}

__global__ void k_scatter(const int* __restrict__ dst, const int* __restrict__ src,
                          int* __restrict__ cursor, int* __restrict__ esrc, int ne) {
  int i = blockIdx.x * 256 + threadIdx.x;
  if (i < ne) { int p = atomicAdd(&cursor[dst[i]], 1); esrc[p] = src[i]; }
}

// ------ bf16 MFMA GEMM + fused el/er; z written as fp8 e4m3 ---------------
// 128x128 tile, BK=32, 4 waves, double-buffered LDS.
__global__ __launch_bounds__(256) void k_gemm_bf16(const __hip_bfloat16* __restrict__ A,
                                                   const __hip_bfloat16* __restrict__ Bt,
                                                   unsigned char* __restrict__ C,
                                                   const float* __restrict__ al,
                                                   const float* __restrict__ ar,
                                                   float* __restrict__ el,
                                                   float* __restrict__ er) {
  __shared__ __hip_bfloat16 As[2][128 * 32];
  __shared__ __hip_bfloat16 Bs[2][128 * 32];
  int tid = threadIdx.x;
  int bm = blockIdx.x * 128;
  int bn = blockIdx.y * 128;
  int w = tid >> 6;
  int l = tid & 63;
  int wr = w >> 1, wc = w & 1;
  int lr = l & 15;
  int lk = (l >> 4) * 8;
  f32x4 acc[4][4] = {};

  const __hip_bfloat16* gA[2];
  const __hip_bfloat16* gB[2];
  int ldsoff[2];
#pragma unroll
  for (int i = 0; i < 2; i++) {
    int idx = i * 256 + tid;
    int row = idx >> 2;
    int ck = (idx & 3) * 8;
    gA[i] = A + (size_t)(bm + row) * KDIM + ck;
    gB[i] = Bt + (size_t)(bn + row) * KDIM + ck;
    ldsoff[i] = idx * 8;
  }

  auto stage = [&](int buf, int k0) {
#pragma unroll
    for (int i = 0; i < 2; i++) GLOAD_LDS16(gA[i] + k0, &As[buf][ldsoff[i]]);
#pragma unroll
    for (int i = 0; i < 2; i++) GLOAD_LDS16(gB[i] + k0, &Bs[buf][ldsoff[i]]);
  };

  stage(0, 0);
  __syncthreads();

  constexpr int NT = KDIM / 32;          // 24 K-steps
  for (int t = 0; t < NT; t++) {
    int cur = t & 1;
    if (t < NT - 1) stage(cur ^ 1, (t + 1) * 32);
    short8v a_frag[4], b_frag[4];
#pragma unroll
    for (int m = 0; m < 4; m++)
      a_frag[m] = *(const short8v*)&As[cur][(wr * 64 + m * 16 + lr) * 32 + lk];
#pragma unroll
    for (int n = 0; n < 4; n++)
      b_frag[n] = *(const short8v*)&Bs[cur][(wc * 64 + n * 16 + lr) * 32 + lk];
#pragma unroll
    for (int m = 0; m < 4; m++)
#pragma unroll
      for (int n = 0; n < 4; n++)
        acc[m][n] = __builtin_amdgcn_mfma_f32_16x16x32_bf16(a_frag[m], b_frag[n], acc[m][n], 0, 0, 0);
    __syncthreads();
  }

  // per-lane al/ar for this block's columns: col = bn + wc*64 + n*16 + lr
  float alv[4], arv[4];
#pragma unroll
  for (int n = 0; n < 4; n++) {
    int col = bn + wc * 64 + n * 16 + lr;
    alv[n] = al[col]; arv[n] = ar[col];
  }
  // C/D layout: col = lane&15, row = (lane>>4)*4 + r  [verified m89/m91]
#pragma unroll
  for (int m = 0; m < 4; m++) {
    int rbase = bm + wr * 64 + m * 16 + (l >> 4) * 4;
#pragma unroll
    for (int n = 0; n < 4; n++) {
      int col = bn + wc * 64 + n * 16 + lr;
#pragma unroll
      for (int r = 0; r < 4; r++) {
        float v = acc[m][n][r];
        int pk = __builtin_amdgcn_cvt_pk_fp8_f32(v, v, 0, false);
        C[(size_t)(rbase + r) * H_ + col] = (unsigned char)(pk & 0xff);
      }
    }
    // fused el/er partials: reduce over the 16 lanes of each row group
#pragma unroll
    for (int r = 0; r < 4; r++) {
      float pel = 0.f, per_ = 0.f;
#pragma unroll
      for (int n = 0; n < 4; n++) {
        pel  += acc[m][n][r] * alv[n];
        per_ += acc[m][n][r] * arv[n];
      }
#pragma unroll
      for (int off2 = 1; off2 < 16; off2 <<= 1) {
        pel  += __shfl_xor(pel,  off2);
        per_ += __shfl_xor(per_, off2);
      }
      if (lr == 0) {
        atomicAdd(&el[rbase + r], pel);
        atomicAdd(&er[rbase + r], per_);
      }
    }
  }
}

// ------- wave-per-dst-node softmax + weighted agg (fp8 z) + elu -----------
__global__ __launch_bounds__(256) void k_agg(const unsigned char* __restrict__ z,
                                             const float* __restrict__ el,
                                             const float* __restrict__ er,
                                             const int* __restrict__ offs,
                                             const int* __restrict__ esrc,
                                             __hip_bfloat16* __restrict__ hout) {
  int wv = threadIdx.x >> 6, lane = threadIdx.x & 63;
  int n = blockIdx.x * 4 + wv;
  int o0 = offs[n];
  int deg = offs[n + 1] - o0;
  float ern = er[n];
  float acc[12] = {};

  if (deg <= 64) {
    float w_ = 0.f; int s_ = 0;
    if (lane < deg) {
      s_ = esrc[o0 + lane];
      float v = el[s_] + ern;
      w_ = v > 0.f ? v : NEG_SLOPE * v;
    } else {
      w_ = -1e30f;
    }
    float m = w_;
    for (int off = 32; off; off >>= 1) m = fmaxf(m, __shfl_xor(m, off));
    float ex = (lane < deg) ? __expf(w_ - m) : 0.f;
    float sum = ex;
    for (int off = 32; off; off >>= 1) sum += __shfl_xor(sum, off);
    w_ = ex / sum;
    for (int j = 0; j < deg; j++) {
      float wj = __shfl(w_, j);
      int sj = __shfl(s_, j);
      const unsigned* zr = (const unsigned*)(z + (size_t)sj * H_);
#pragma unroll
      for (int i = 0; i < 3; i++) {
        unsigned u = zr[lane + i * 64];
        acc[i * 4 + 0] += wj * __builtin_amdgcn_cvt_f32_fp8(u, 0);
        acc[i * 4 + 1] += wj * __builtin_amdgcn_cvt_f32_fp8(u, 1);
        acc[i * 4 + 2] += wj * __builtin_amdgcn_cvt_f32_fp8(u, 2);
        acc[i * 4 + 3] += wj * __builtin_amdgcn_cvt_f32_fp8(u, 3);
      }
    }
  } else {
    float lmax = -1e30f;
    for (int i = lane; i < deg; i += 64) {
      float v = el[esrc[o0 + i]] + ern;
      v = v > 0.f ? v : NEG_SLOPE * v;
      lmax = fmaxf(lmax, v);
    }
    for (int off = 32; off; off >>= 1) lmax = fmaxf(lmax, __shfl_xor(lmax, off));
    float lsum = 0.f;
    for (int i = lane; i < deg; i += 64) {
      float v = el[esrc[o0 + i]] + ern;
      v = v > 0.f ? v : NEG_SLOPE * v;
      lsum += __expf(v - lmax);
    }
    for (int off = 32; off; off >>= 1) lsum += __shfl_xor(lsum, off);
    float inv = 1.0f / lsum;
    for (int base = 0; base < deg; base += 64) {
      int chunk = min(64, deg - base);
      float w_ = 0.f; int s_ = 0;
      if (lane < chunk) {
        s_ = esrc[o0 + base + lane];
        float v = el[s_] + ern;
        v = v > 0.f ? v : NEG_SLOPE * v;
        w_ = __expf(v - lmax) * inv;
      }
      for (int j = 0; j < chunk; j++) {
        float wj = __shfl(w_, j);
        int sj = __shfl(s_, j);
        const unsigned* zr = (const unsigned*)(z + (size_t)sj * H_);
#pragma unroll
        for (int i = 0; i < 3; i++) {
          unsigned u = zr[lane + i * 64];
          acc[i * 4 + 0] += wj * __builtin_amdgcn_cvt_f32_fp8(u, 0);
          acc[i * 4 + 1] += wj * __builtin_amdgcn_cvt_f32_fp8(u, 1);
          acc[i * 4 + 2] += wj * __builtin_amdgcn_cvt_f32_fp8(u, 2);
          acc[i * 4 + 3] += wj * __builtin_amdgcn_cvt_f32_fp8(u, 3);
        }
      }
    }
  }

  short4* ho = (short4*)(hout + (size_t)n * H_);
#pragma unroll
  for (int i = 0; i < 3; i++) {
    float e0 = acc[i * 4 + 0]; e0 = e0 > 0.f ? e0 : __expf(e0) - 1.f;
    float e1 = acc[i * 4 + 1]; e1 = e1 > 0.f ? e1 : __expf(e1) - 1.f;
    float e2 = acc[i * 4 + 2]; e2 = e2 > 0.f ? e2 : __expf(e2) - 1.f;
    float e3 = acc[i * 4 + 3]; e3 = e3 > 0.f ? e3 : __expf(e3) - 1.f;
    short4 o; o.x = f2bf(e0); o.y = f2bf(e1); o.z = f2bf(e2); o.w = f2bf(e3);
    ho[lane + i * 64] = o;
  }
}

// ------- fused doc reductions: grid (B, 16): y<8 -> avg, y>=8 -> qf -------
__global__ __launch_bounds__(192) void k_avgqf(const __hip_bfloat16* __restrict__ h,
                                               const float* __restrict__ features,
                                               const int* __restrict__ masks,
                                               const int* __restrict__ segment_ids,
                                               const int* __restrict__ is_head,
                                               const int* __restrict__ doc_spans,
                                               float* __restrict__ avgp,
                                               float* __restrict__ qfp) {
  int b = blockIdx.x;
  int y = blockIdx.y;
  int tid = threadIdx.x;
  int d = docof(b, doc_spans);
  if (y < 8) {
    int s0 = y * 16;
    float4 a = make_float4(0.f, 0.f, 0.f, 0.f);
    for (int i = 0; i < 16; i++) {
      short4 v = ((const short4*)(h + ((size_t)(b * S_ + s0 + i)) * H_))[tid];
      a.x += bf2f(v.x); a.y += bf2f(v.y); a.z += bf2f(v.z); a.w += bf2f(v.w);
    }
    atomicAdd(&avgp[d * H_ + tid * 4 + 0], a.x);
    atomicAdd(&avgp[d * H_ + tid * 4 + 1], a.y);
    atomicAdd(&avgp[d * H_ + tid * 4 + 2], a.z);
    atomicAdd(&avgp[d * H_ + tid * 4 + 3], a.w);
  } else {
    int l0 = (y - 8) * 64;
    __shared__ float qm[64];
    if (tid < 64) {
      int l = l0 + tid;
      qm[tid] = (is_head[b * L_ + l] != 2 && segment_ids[b * L_ + l] == 0 && masks[b * L_ + l] > 0) ? 1.0f : 0.0f;
    }
    __syncthreads();
    float4 a = make_float4(0.f, 0.f, 0.f, 0.f);
    for (int i = 0; i < 64; i++) {
      if (qm[i] != 0.f) {
        float4 v = ((const float4*)(features + ((size_t)b * L_ + l0 + i) * H_))[tid];
        a.x += v.x; a.y += v.y; a.z += v.z; a.w += v.w;
      }
    }
    atomicAdd(&qfp[d * H_ + tid * 4 + 0], a.x);
    atomicAdd(&qfp[d * H_ + tid * 4 + 1], a.y);
    atomicAdd(&qfp[d * H_ + tid * 4 + 2], a.z);
    atomicAdd(&qfp[d * H_ + tid * 4 + 3], a.w);
  }
}

// ---------------- final: out[d] = sum_h |qf/doccnt - avg/nodecnt| ----------
__global__ __launch_bounds__(512) void k_final(const float* __restrict__ qfp,
                                               const float* __restrict__ avgp,
                                               const int* __restrict__ doc_spans,
                                               float* __restrict__ out) {
  __shared__ int ds[D_ * 2];
  int tid = threadIdx.x;
  if (tid < D_ * 2) ds[tid] = doc_spans[tid];
  __syncthreads();
  int d = tid >> 6, lane = tid & 63;
  int nsent = 0;
  for (int b = 0; b < B_; b++) {
    int cnt = 0;
#pragma unroll
    for (int dd = 0; dd < D_; dd++) cnt += (ds[dd * 2] <= b) ? 1 : 0;
    nsent += ((cnt - 1) == d) ? 1 : 0;
  }
  float inv_node = 1.0f / fmaxf((float)nsent * (float)S_, 1.0f);
  float inv_doc  = 1.0f / fmaxf((float)(ds[d * 2 + 1] - ds[d * 2]), 1.0f);
  float acc = 0.f;
  for (int h = lane; h < H_; h += 64)
    acc += fabsf(qfp[d * H_ + h] * inv_doc - avgp[d * H_ + h] * inv_node);
  for (int off = 32; off; off >>= 1) acc += __shfl_xor(acc, off);
  if (lane == 0) out[d] = acc;
}

extern "C" void kernel_launch(void* const* d_in, const int* in_sizes, int n_in,
                              void* d_out, int out_size, void* d_ws, size_t ws_size,
                              hipStream_t stream) {
  const float* features     = (const float*)d_in[0];
  const int*   token_spans  = (const int*)d_in[1];
  const int*   masks        = (const int*)d_in[2];
  const int*   selidx       = (const int*)d_in[3];
  const int*   src          = (const int*)d_in[4];
  const int*   dst          = (const int*)d_in[5];
  const int*   doc_spans    = (const int*)d_in[6];
  const int*   segment_ids  = (const int*)d_in[7];
  const int*   is_head      = (const int*)d_in[8];
  const float* Wl[3]  = {(const float*)d_in[9],  (const float*)d_in[12], (const float*)d_in[15]};
  const float* alv[3] = {(const float*)d_in[10], (const float*)d_in[13], (const float*)d_in[16]};
  const float* arv[3] = {(const float*)d_in[11], (const float*)d_in[14], (const float*)d_in[17]};
  float* out = (float*)d_out;

  char* ws = (char*)d_ws;
  size_t off = 0;
  auto alloc = [&](size_t bytes) -> void* {
    void* p = ws + off;
    off = (off + bytes + 255) & ~(size_t)255;
    return p;
  };
  __hip_bfloat16* hA = (__hip_bfloat16*)alloc((size_t)N_ * H_ * 2);   // bf16 h
  unsigned char*  hB = (unsigned char*)alloc((size_t)N_ * H_);        // fp8 z
  __hip_bfloat16* Wt = (__hip_bfloat16*)alloc((size_t)3 * H_ * H_ * 2);
  // ---- contiguous zero-fill region: avgp|qfp | el[3] | er[3] | counts ----
  float* avgp   = (float*)alloc((size_t)2 * D_ * H_ * 4);  // avgp | qfp
  float* qfp    = avgp + (size_t)D_ * H_;
  float* el     = (float*)alloc((size_t)3 * N_ * 4);
  float* er     = (float*)alloc((size_t)3 * N_ * 4);
  int*   counts = (int*)alloc((size_t)N_ * 4);
  // total = (2*8*768 + 6*8192 + 8192)*4 = 278528 B = 68 blocks * 256 * 16 B
  int*   offs   = (int*)alloc((size_t)(N_ + 1) * 4);
  int*   cursor = (int*)alloc((size_t)N_ * 4);
  int*   esrc   = (int*)alloc((size_t)NE_ * 4);

  // token pooling + W transposes + zero-fill in one dispatch (runs FIRST:
  // zeroes counts before k_count, el/er before gemm, avgp/qfp before avgqf)
  k_token_wt<<<N_ + NB_WT + NB_ZERO, 256, 0, stream>>>(features, token_spans, masks, selidx,
                                                       hA, Wl[0], Wl[1], Wl[2], Wt,
                                                       (int4*)avgp);

  // CSR build (edges constant across layers)
  k_count<<<(NE_ + 255) / 256, 256, 0, stream>>>(dst, counts, NE_);
  k_scan<<<1, 1024, 0, stream>>>(counts, offs, cursor);
  k_scatter<<<(NE_ + 255) / 256, 256, 0, stream>>>(dst, src, cursor, esrc, NE_);

  // 3 GAT layers: hA(bf16) -> z(hB,fp8)+el/er -> hA(bf16)
  for (int i = 0; i < 3; i++) {
    k_gemm_bf16<<<dim3(N_ / 128, H_ / 128), 256, 0, stream>>>(
        hA, Wt + (size_t)i * H_ * H_, hB, alv[i], arv[i],
        el + (size_t)i * N_, er + (size_t)i * N_);
    k_agg<<<N_ / 4, 256, 0, stream>>>(hB, el + (size_t)i * N_, er + (size_t)i * N_,
                                      offs, esrc, hA);
  }

  // doc-level reductions (avg + qf fused)
  k_avgqf<<<dim3(B_, 16), 192, 0, stream>>>(hA, features, masks, segment_ids, is_head,
                                            doc_spans, avgp, qfp);
  k_final<<<1, 512, 0, stream>>>(qfp, avgp, doc_spans, out);
}